// Round 1
// baseline (124.726 us; speedup 1.0000x reference)
//
#include <hip/hip_runtime.h>

// Focal loss (adaptive gamma) forward, sum-reduced.
// input: [N, C] float32, target: [N] int32, out: scalar float32.
// N=32768, C=4096 in the harness; kernel assumes C == 4096 (asserted by layout).

#define THREADS 256
#define CCONST 4096
#define ELEMS_PER_THREAD (CCONST / THREADS)   // 16 -> 4x float4

__global__ __launch_bounds__(THREADS) void focal_row_kernel(
    const float* __restrict__ inp,
    const int* __restrict__ target,
    float* __restrict__ partial)
{
    const int row = blockIdx.x;
    const int t = threadIdx.x;
    const float4* rowp = reinterpret_cast<const float4*>(inp + (size_t)row * CCONST);

    // One coalesced pass: 4 x float4 per thread, strided by blockDim.
    float4 v[4];
#pragma unroll
    for (int k = 0; k < 4; ++k)
        v[k] = rowp[t + THREADS * k];

    // --- row max ---
    float m = -INFINITY;
#pragma unroll
    for (int k = 0; k < 4; ++k) {
        m = fmaxf(m, fmaxf(fmaxf(v[k].x, v[k].y), fmaxf(v[k].z, v[k].w)));
    }
#pragma unroll
    for (int off = 32; off > 0; off >>= 1)
        m = fmaxf(m, __shfl_xor(m, off));

    __shared__ float smax[THREADS / 64];
    __shared__ float ssum[THREADS / 64];
    const int wave = t >> 6;
    if ((t & 63) == 0) smax[wave] = m;
    __syncthreads();
    m = fmaxf(fmaxf(smax[0], smax[1]), fmaxf(smax[2], smax[3]));

    // --- sum of exp(x - m), from registers (no second global pass) ---
    float s = 0.0f;
#pragma unroll
    for (int k = 0; k < 4; ++k) {
        s += __expf(v[k].x - m) + __expf(v[k].y - m)
           + __expf(v[k].z - m) + __expf(v[k].w - m);
    }
#pragma unroll
    for (int off = 32; off > 0; off >>= 1)
        s += __shfl_xor(s, off);
    if ((t & 63) == 0) ssum[wave] = s;
    __syncthreads();

    if (t == 0) {
        float sum = ssum[0] + ssum[1] + ssum[2] + ssum[3];
        int c = target[row];
        float xt = inp[(size_t)row * CCONST + c];
        float logpt = xt - m - __logf(sum);
        float pt = __expf(logpt);
        float u = 1.0f - pt;
        float w;
        if (pt >= 0.5f) {
            w = 1.0f;                    // gamma = 0
        } else if (pt < 0.2f) {
            float u2 = u * u;            // gamma = 5
            w = u2 * u2 * u;
        } else {
            w = u * u * u;               // gamma = 3
        }
        partial[row] = -w * logpt;
    }
}

// Deterministic fixed-tree reduction of N partials -> scalar.
__global__ __launch_bounds__(THREADS) void focal_reduce_kernel(
    const float* __restrict__ partial,
    float* __restrict__ out,
    int n)
{
    const int t = threadIdx.x;
    float s = 0.0f;
    for (int i = t; i < n; i += THREADS)
        s += partial[i];

#pragma unroll
    for (int off = 32; off > 0; off >>= 1)
        s += __shfl_xor(s, off);

    __shared__ float ssum[THREADS / 64];
    if ((t & 63) == 0) ssum[t >> 6] = s;
    __syncthreads();
    if (t == 0)
        out[0] = ssum[0] + ssum[1] + ssum[2] + ssum[3];
}

extern "C" void kernel_launch(void* const* d_in, const int* in_sizes, int n_in,
                              void* d_out, int out_size, void* d_ws, size_t ws_size,
                              hipStream_t stream)
{
    const float* inp    = (const float*)d_in[0];
    const int*   target = (const int*)d_in[1];
    float* out = (float*)d_out;
    float* partial = (float*)d_ws;          // N floats of scratch

    const int N = in_sizes[1];              // 32768 rows

    focal_row_kernel<<<N, THREADS, 0, stream>>>(inp, target, partial);
    focal_reduce_kernel<<<1, THREADS, 0, stream>>>(partial, out, N);
}

// Round 2
// 102.660 us; speedup vs baseline: 1.2149x; 1.2149x over previous
//
#include <hip/hip_runtime.h>

// Focal loss (adaptive gamma) forward, sum-reduced.
// input: [N, C] float32, target: [N] int32, out: scalar float32.
// Harness: N=32768, C=4096. Kernel assumes C == 4096.
//
// Design: one 64-lane wave per row (16x float4 per lane, registers only),
// 4 rows per 256-thread block, NO barriers / NO LDS in the row kernel.
// All reductions are wave-level __shfl_xor butterflies.

#define CCONST 4096
#define ROW_THREADS 256
#define ROWS_PER_BLOCK 4            // one wave each

__global__ __launch_bounds__(ROW_THREADS) void focal_row_kernel(
    const float* __restrict__ inp,
    const int* __restrict__ target,
    float* __restrict__ partial,
    int n_rows)
{
    const int lane = threadIdx.x & 63;
    const int wave = threadIdx.x >> 6;
    const int row  = blockIdx.x * ROWS_PER_BLOCK + wave;
    if (row >= n_rows) return;

    const float4* rowp = reinterpret_cast<const float4*>(inp + (size_t)row * CCONST);

    // One coalesced pass: 16 x float4 per lane (64 elems), all loads in flight.
    float4 v[16];
#pragma unroll
    for (int k = 0; k < 16; ++k)
        v[k] = rowp[lane + 64 * k];

    // Target gather (wave-uniform address -> broadcast transactions).
    const int c  = target[row];
    const float xt = inp[(size_t)row * CCONST + c];

    // --- row max (registers -> 6-step butterfly) ---
    float m = -INFINITY;
#pragma unroll
    for (int k = 0; k < 16; ++k)
        m = fmaxf(m, fmaxf(fmaxf(v[k].x, v[k].y), fmaxf(v[k].z, v[k].w)));
#pragma unroll
    for (int off = 32; off > 0; off >>= 1)
        m = fmaxf(m, __shfl_xor(m, off));

    // --- sum of exp(x - m), still from registers ---
    float s = 0.0f;
#pragma unroll
    for (int k = 0; k < 16; ++k) {
        s += __expf(v[k].x - m) + __expf(v[k].y - m)
           + __expf(v[k].z - m) + __expf(v[k].w - m);
    }
#pragma unroll
    for (int off = 32; off > 0; off >>= 1)
        s += __shfl_xor(s, off);

    if (lane == 0) {
        float logpt = xt - m - __logf(s);
        float pt = __expf(logpt);
        float u = 1.0f - pt;
        float w;
        if (pt >= 0.5f) {
            w = 1.0f;                    // gamma = 0
        } else if (pt < 0.2f) {
            float u2 = u * u;            // gamma = 5
            w = u2 * u2 * u;
        } else {
            w = u * u * u;               // gamma = 3
        }
        partial[row] = -w * logpt;
    }
}

// Deterministic fixed-tree reduction of N partials -> scalar. 1024 threads.
#define RED_THREADS 1024
__global__ __launch_bounds__(RED_THREADS) void focal_reduce_kernel(
    const float* __restrict__ partial,
    float* __restrict__ out,
    int n)
{
    const int t = threadIdx.x;
    float s = 0.0f;
#pragma unroll 4
    for (int i = t; i < n; i += RED_THREADS)
        s += partial[i];

#pragma unroll
    for (int off = 32; off > 0; off >>= 1)
        s += __shfl_xor(s, off);

    __shared__ float ssum[RED_THREADS / 64];
    if ((t & 63) == 0) ssum[t >> 6] = s;
    __syncthreads();
    if (t == 0) {
        float tot = 0.0f;
#pragma unroll
        for (int i = 0; i < RED_THREADS / 64; ++i)
            tot += ssum[i];
        out[0] = tot;
    }
}

extern "C" void kernel_launch(void* const* d_in, const int* in_sizes, int n_in,
                              void* d_out, int out_size, void* d_ws, size_t ws_size,
                              hipStream_t stream)
{
    const float* inp    = (const float*)d_in[0];
    const int*   target = (const int*)d_in[1];
    float* out = (float*)d_out;
    float* partial = (float*)d_ws;          // N floats of scratch

    const int N = in_sizes[1];              // 32768 rows

    const int blocks = (N + ROWS_PER_BLOCK - 1) / ROWS_PER_BLOCK;
    focal_row_kernel<<<blocks, ROW_THREADS, 0, stream>>>(inp, target, partial, N);
    focal_reduce_kernel<<<1, RED_THREADS, 0, stream>>>(partial, out, N);
}